// Round 1
// baseline (1109.376 us; speedup 1.0000x reference)
//
#include <hip/hip_runtime.h>
#include <cstdint>
#include <cstddef>

// EncoderLayer: x(4,2048,1024) f32.
// Pipeline (all bf16-MFMA GEMMs, f32 accum):
//   prep:  W* (KxN f32) -> W*T (NxK bf16)   [4 transpose-convert launches]
//          x f32 -> xb bf16
//   G1: qkv_b  = xb @ WqkvT + bqkv              (8192x3072, bf16 out)
//   attn: per-position 16x16 head attention, out in (N,H,S,hd) order = scrambled reshape
//   G2: ao2    = aob @ WoT + bo                 (8192x1024, f32 out)
//   LN1: h = LN(ao2 + x)  -> h_f (f32) + h_b (bf16)
//   G3: ff1_b  = relu(h_b @ W1T + bf1)          (8192x4096, bf16 out)
//   G4: ff2    = ff1_b @ W2T + bf2              (8192x1024, f32 out)
//   LN2: out = LN(ff2 + h_f)                    (f32 -> d_out)

using f32x4  = __attribute__((ext_vector_type(4))) float;
using bf16x8 = __attribute__((ext_vector_type(8))) __bf16;

__device__ __forceinline__ unsigned short f2b(float f) {
  union { float f; uint32_t u; } v; v.f = f;
  uint32_t r = v.u + 0x7FFFu + ((v.u >> 16) & 1u);  // RNE
  return (unsigned short)(r >> 16);
}
__device__ __forceinline__ float b2f(unsigned short u) {
  union { uint32_t u; float f; } v; v.u = ((uint32_t)u) << 16;
  return v.f;
}

// ---------------- weight transpose + convert: W (KxN f32) -> WT (NxK bf16) ----
__global__ __launch_bounds__(256) void transpose_cvt_kernel(
    const float* __restrict__ W, unsigned short* __restrict__ WT, int K, int N) {
  __shared__ float tile[32][33];
  const int j0 = blockIdx.x * 32, k0 = blockIdx.y * 32;
  const int tx = threadIdx.x, ty = threadIdx.y;
#pragma unroll
  for (int i = 0; i < 4; ++i)
    tile[ty + 8 * i][tx] = W[(size_t)(k0 + ty + 8 * i) * N + j0 + tx];
  __syncthreads();
#pragma unroll
  for (int i = 0; i < 4; ++i)
    WT[(size_t)(j0 + ty + 8 * i) * K + k0 + tx] = f2b(tile[tx][ty + 8 * i]);
}

// ---------------- f32 -> bf16 elementwise ------------------------------------
__global__ __launch_bounds__(256) void cvt_bf16_kernel(
    const float* __restrict__ in, unsigned short* __restrict__ out, int n4) {
  for (int i = blockIdx.x * blockDim.x + threadIdx.x; i < n4;
       i += gridDim.x * blockDim.x) {
    float4 v = ((const float4*)in)[i];
    uint32_t lo = (uint32_t)f2b(v.x) | ((uint32_t)f2b(v.y) << 16);
    uint32_t hi = (uint32_t)f2b(v.z) | ((uint32_t)f2b(v.w) << 16);
    ((uint2*)out)[i] = make_uint2(lo, hi);
  }
}

// ---------------- GEMM: C(MxN) = A(MxK,bf16) * B^T(NxK,bf16) + bias ----------
// 128x128 tile, BK=64, 4 waves (2x2), each wave 64x64 via 4x4 mfma_16x16x32_bf16.
// LDS XOR-swizzle: physical 16B chunk p holds logical chunk (p ^ (row&7)).
template <bool OUTB, bool RELU>
__global__ __launch_bounds__(256, 2) void gemm_kernel(
    const unsigned short* __restrict__ A, const unsigned short* __restrict__ B,
    const float* __restrict__ bias, void* __restrict__ C, int M, int N, int K) {
  __shared__ unsigned short As[128 * 64];
  __shared__ unsigned short Bs[128 * 64];
  const int tid = threadIdx.x;
  const int lane = tid & 63, wave = tid >> 6;
  const int wm = wave >> 1, wn = wave & 1;
  const int lr = lane & 15, lk = lane >> 4;
  const int bm = blockIdx.y, bn = blockIdx.x;

  const int srow = tid >> 3;  // staging row 0..31 (+32 per it)
  const int sp   = tid & 7;   // physical 16B slot

  const unsigned short* Ab = A + (size_t)bm * 128 * K;
  const unsigned short* Bb = B + (size_t)bn * 128 * K;

  f32x4 acc[4][4] = {};

  for (int kt = 0; kt < K; kt += 64) {
    uint4 ra[4], rb[4];
#pragma unroll
    for (int it = 0; it < 4; ++it) {
      int row = srow + it * 32;
      int lc = sp ^ (row & 7);  // logical chunk for this physical slot
      ra[it] = *(const uint4*)(Ab + (size_t)row * K + kt + lc * 8);
      rb[it] = *(const uint4*)(Bb + (size_t)row * K + kt + lc * 8);
    }
    __syncthreads();  // previous iteration's LDS reads done
#pragma unroll
    for (int it = 0; it < 4; ++it) {
      int row = srow + it * 32;
      *(uint4*)&As[row * 64 + sp * 8] = ra[it];
      *(uint4*)&Bs[row * 64 + sp * 8] = rb[it];
    }
    __syncthreads();
#pragma unroll
    for (int kk = 0; kk < 2; ++kk) {
      bf16x8 af[4], bfr[4];
#pragma unroll
      for (int f = 0; f < 4; ++f) {
        int ar = wm * 64 + f * 16 + lr;
        int ac = (kk * 4 + lk) ^ (ar & 7);
        af[f] = *(const bf16x8*)&As[ar * 64 + ac * 8];
        int br = wn * 64 + f * 16 + lr;
        int bc = (kk * 4 + lk) ^ (br & 7);
        bfr[f] = *(const bf16x8*)&Bs[br * 64 + bc * 8];
      }
#pragma unroll
      for (int mi = 0; mi < 4; ++mi)
#pragma unroll
        for (int ni = 0; ni < 4; ++ni)
          acc[mi][ni] = __builtin_amdgcn_mfma_f32_16x16x32_bf16(
              af[mi], bfr[ni], acc[mi][ni], 0, 0, 0);
    }
  }

  // epilogue: C/D frag layout col = lane&15, row = (lane>>4)*4 + reg
  const int orow0 = bm * 128 + wm * 64;
  const int ocol0 = bn * 128 + wn * 64;
#pragma unroll
  for (int ni = 0; ni < 4; ++ni) {
    int col = ocol0 + ni * 16 + lr;
    float bv = bias[col];
#pragma unroll
    for (int mi = 0; mi < 4; ++mi) {
#pragma unroll
      for (int r = 0; r < 4; ++r) {
        int row = orow0 + mi * 16 + lk * 4 + r;
        float val = acc[mi][ni][r] + bv;
        if (RELU) val = fmaxf(val, 0.f);
        if (OUTB)
          ((unsigned short*)C)[(size_t)row * N + col] = f2b(val);
        else
          ((float*)C)[(size_t)row * N + col] = val;
      }
    }
  }
}

// ---------------- per-position head attention --------------------------------
// One block per (n,s). E[i][j] = q_i . k_j (hd=64), mask over j, softmax_j,
// O[i][d] = sum_l p[i][l] v[l][d]; stored in (N,H,S,hd) order (scrambled reshape).
__global__ __launch_bounds__(256) void attn_kernel(
    const unsigned short* __restrict__ qkv, const int* __restrict__ mask,
    unsigned short* __restrict__ outb) {
  __shared__ float sq[16][68], sk[16][68], sv[16][68];
  __shared__ float sp[16][17];
  const int pos = blockIdx.x;           // n*2048 + s
  const int n = pos >> 11, s = pos & 2047;
  const int tid = threadIdx.x;
  const unsigned short* row = qkv + (size_t)pos * 3072;
#pragma unroll
  for (int it = 0; it < 3; ++it) {
    uint2 raw = *(const uint2*)(row + it * 1024 + tid * 4);
    float f0 = b2f((unsigned short)(raw.x & 0xffffu));
    float f1 = b2f((unsigned short)(raw.x >> 16));
    float f2 = b2f((unsigned short)(raw.y & 0xffffu));
    float f3 = b2f((unsigned short)(raw.y >> 16));
    float(*dst)[68] = (it == 0) ? sq : (it == 1) ? sk : sv;
    int r = tid >> 4, d = (tid & 15) * 4;
    dst[r][d] = f0; dst[r][d + 1] = f1; dst[r][d + 2] = f2; dst[r][d + 3] = f3;
  }
  __syncthreads();
  {
    const int i = tid >> 4, j = tid & 15;
    float e = 0.f;
#pragma unroll
    for (int d = 0; d < 64; d += 4) {
      float4 qa = *(const float4*)&sq[i][d];
      float4 kb = *(const float4*)&sk[j][d];
      e += qa.x * kb.x + qa.y * kb.y + qa.z * kb.z + qa.w * kb.w;
    }
    if (mask[n * 16 + j] == 0) e = -1e20f;
    e *= 0.125f;  // 1/sqrt(64)
    float mx = e;
#pragma unroll
    for (int o = 8; o > 0; o >>= 1) mx = fmaxf(mx, __shfl_xor(mx, o, 16));
    float pe = __expf(e - mx);
    float sm = pe;
#pragma unroll
    for (int o = 8; o > 0; o >>= 1) sm += __shfl_xor(sm, o, 16);
    sp[i][j] = pe / sm;
  }
  __syncthreads();
  {
    const int w = tid >> 6, d = tid & 63;
    float o0 = 0, o1 = 0, o2 = 0, o3 = 0;
#pragma unroll
    for (int l = 0; l < 16; ++l) {
      float vv = sv[l][d];
      o0 += sp[w][l] * vv;      o1 += sp[w + 4][l] * vv;
      o2 += sp[w + 8][l] * vv;  o3 += sp[w + 12][l] * vv;
    }
    outb[(((size_t)n * 16 + w     ) * 2048 + s) * 64 + d] = f2b(o0);
    outb[(((size_t)n * 16 + w + 4 ) * 2048 + s) * 64 + d] = f2b(o1);
    outb[(((size_t)n * 16 + w + 8 ) * 2048 + s) * 64 + d] = f2b(o2);
    outb[(((size_t)n * 16 + w + 12) * 2048 + s) * 64 + d] = f2b(o3);
  }
}

// ---------------- LayerNorm(A + R) * g + beta --------------------------------
__global__ __launch_bounds__(256) void ln_kernel(
    const float* __restrict__ A, const float* __restrict__ R,
    const float* __restrict__ g, const float* __restrict__ be,
    float* __restrict__ outf, unsigned short* __restrict__ outb) {
  const int row = blockIdx.x, tid = threadIdx.x;
  const size_t base = (size_t)row * 1024 + tid * 4;
  float4 a = *(const float4*)(A + base);
  float4 r = *(const float4*)(R + base);
  float x0 = a.x + r.x, x1 = a.y + r.y, x2 = a.z + r.z, x3 = a.w + r.w;
  float s = x0 + x1 + x2 + x3;
#pragma unroll
  for (int o = 32; o > 0; o >>= 1) s += __shfl_xor(s, o);
  __shared__ float red[4];
  const int lane = tid & 63, wv = tid >> 6;
  if (lane == 0) red[wv] = s;
  __syncthreads();
  float mean = (red[0] + red[1] + red[2] + red[3]) * (1.f / 1024.f);
  float d0 = x0 - mean, d1 = x1 - mean, d2 = x2 - mean, d3 = x3 - mean;
  float q = d0 * d0 + d1 * d1 + d2 * d2 + d3 * d3;
#pragma unroll
  for (int o = 32; o > 0; o >>= 1) q += __shfl_xor(q, o);
  __syncthreads();  // everyone done reading red
  if (lane == 0) red[wv] = q;
  __syncthreads();
  float var = (red[0] + red[1] + red[2] + red[3]) * (1.f / 1024.f);
  float rs = rsqrtf(var + 1e-5f);
  const int col = tid * 4;
  float4 gv = *(const float4*)(g + col);
  float4 bv = *(const float4*)(be + col);
  float y0 = d0 * rs * gv.x + bv.x;
  float y1 = d1 * rs * gv.y + bv.y;
  float y2 = d2 * rs * gv.z + bv.z;
  float y3 = d3 * rs * gv.w + bv.w;
  *(float4*)(outf + base) = make_float4(y0, y1, y2, y3);
  if (outb) {
    uint32_t lo = (uint32_t)f2b(y0) | ((uint32_t)f2b(y1) << 16);
    uint32_t hi = (uint32_t)f2b(y2) | ((uint32_t)f2b(y3) << 16);
    *(uint2*)(outb + base) = make_uint2(lo, hi);
  }
}

// ---------------- launch ------------------------------------------------------
extern "C" void kernel_launch(void* const* d_in, const int* in_sizes, int n_in,
                              void* d_out, int out_size, void* d_ws,
                              size_t ws_size, hipStream_t stream) {
  (void)in_sizes; (void)n_in; (void)out_size; (void)ws_size;
  const float* x     = (const float*)d_in[0];
  const float* Wqkv  = (const float*)d_in[1];
  const float* bqkv  = (const float*)d_in[2];
  const float* Wo    = (const float*)d_in[3];
  const float* bo    = (const float*)d_in[4];
  const float* g1    = (const float*)d_in[5];
  const float* beta1 = (const float*)d_in[6];
  const float* W1    = (const float*)d_in[7];
  const float* bf1   = (const float*)d_in[8];
  const float* W2    = (const float*)d_in[9];
  const float* bf2   = (const float*)d_in[10];
  const float* g2    = (const float*)d_in[11];
  const float* beta2 = (const float*)d_in[12];
  const int*   mask  = (const int*)d_in[13];
  float* out = (float*)d_out;

  char* ws = (char*)d_ws;
  unsigned short* WqkvT = (unsigned short*)(ws + 0);          //  6 MB
  unsigned short* WoT   = (unsigned short*)(ws + 6291456);    //  2 MB
  unsigned short* W1T   = (unsigned short*)(ws + 8388608);    //  8 MB
  unsigned short* W2T   = (unsigned short*)(ws + 16777216);   //  8 MB
  unsigned short* xb    = (unsigned short*)(ws + 25165824);   // 16 MB
  float*          h_f   = (float*)(ws + 41943040);            // 32 MB
  unsigned short* h_b   = (unsigned short*)(ws + 75497472);   // 16 MB
  float*          ao2   = (float*)(ws + 92274688);            // 32 MB (reused: ff2)
  unsigned short* qkvb  = (unsigned short*)(ws + 125829120);  // 48 MB (reused: ff1 lo)
  unsigned short* aob   = (unsigned short*)(ws + 176160768);  // 16 MB (reused: ff1 hi)
  unsigned short* ff1   = qkvb;   // 64 MB spanning qkvb+aob (dead by then)
  float*          ff2   = ao2;    // dead after LN1
  // total ws use: 192,937,984 bytes

  transpose_cvt_kernel<<<dim3(96, 32),  dim3(32, 8), 0, stream>>>(Wqkv, WqkvT, 1024, 3072);
  transpose_cvt_kernel<<<dim3(32, 32),  dim3(32, 8), 0, stream>>>(Wo,   WoT,   1024, 1024);
  transpose_cvt_kernel<<<dim3(128, 32), dim3(32, 8), 0, stream>>>(W1,   W1T,   1024, 4096);
  transpose_cvt_kernel<<<dim3(32, 128), dim3(32, 8), 0, stream>>>(W2,   W2T,   4096, 1024);
  cvt_bf16_kernel<<<2048, 256, 0, stream>>>(x, xb, 8192 * 1024 / 4);

  gemm_kernel<true, false><<<dim3(24, 64), 256, 0, stream>>>(xb, WqkvT, bqkv, qkvb, 8192, 3072, 1024);
  attn_kernel<<<8192, 256, 0, stream>>>(qkvb, mask, aob);
  gemm_kernel<false, false><<<dim3(8, 64), 256, 0, stream>>>(aob, WoT, bo, ao2, 8192, 1024, 1024);
  ln_kernel<<<8192, 256, 0, stream>>>(ao2, x, g1, beta1, h_f, h_b);
  gemm_kernel<true, true><<<dim3(32, 64), 256, 0, stream>>>(h_b, W1T, bf1, ff1, 8192, 4096, 1024);
  gemm_kernel<false, false><<<dim3(8, 64), 256, 0, stream>>>(ff1, W2T, bf2, ff2, 8192, 1024, 4096);
  ln_kernel<<<8192, 256, 0, stream>>>(ff2, h_f, g2, beta2, out, nullptr);
}

// Round 2
// 408.572 us; speedup vs baseline: 2.7152x; 2.7152x over previous
//
#include <hip/hip_runtime.h>
#include <cstdint>
#include <cstddef>

// EncoderLayer: x(4,2048,1024) f32.
//   prep:  W* (KxN f32) -> W*T (NxK bf16); x f32 -> xb bf16
//   G1: qkv_b  = xb @ WqkvT + bqkv              (8192x3072, bf16 out)
//   attn: per-position 16x16 head attention, out (N,H,S,hd) order = scrambled reshape
//   G2: ao2    = aob @ WoT + bo                 (8192x1024, f32 out)
//   LN1: h = LN(ao2 + x)  -> h_f (f32) + h_b (bf16)
//   G3: ff1_b  = relu(h_b @ W1T + bf1)          (8192x4096, bf16 out)
//   G4: ff2    = ff1_b @ W2T + bf2              (8192x1024, f32 out)
//   LN2: out = LN(ff2 + h_f)                    (f32 -> d_out)
//
// GEMM: BM=256 BN=128 BK=64, 512 thr (8 waves 4Mx2N, 64x64/wave),
// global_load_lds width-16 staging, single-buffer 2-barrier loop (m97
// structure, 874-912 TF verified), XCD-chunked swizzle with bn-fastest rows
// so concurrent blocks on an XCD share one A panel in L2.

using f32x4  = __attribute__((ext_vector_type(4))) float;
using bf16x8 = __attribute__((ext_vector_type(8))) __bf16;

__device__ __forceinline__ unsigned short f2b(float f) {
  union { float f; uint32_t u; } v; v.f = f;
  uint32_t r = v.u + 0x7FFFu + ((v.u >> 16) & 1u);  // RNE
  return (unsigned short)(r >> 16);
}
__device__ __forceinline__ float b2f(unsigned short u) {
  union { uint32_t u; float f; } v; v.u = ((uint32_t)u) << 16;
  return v.f;
}

__device__ __forceinline__ void gload_lds16(const unsigned short* g,
                                            unsigned short* l) {
  __builtin_amdgcn_global_load_lds(
      (const __attribute__((address_space(1))) unsigned int*)g,
      (__attribute__((address_space(3))) unsigned int*)l, 16, 0, 0);
}

// ---------------- weight transpose + convert: W (KxN f32) -> WT (NxK bf16) ----
__global__ __launch_bounds__(256) void transpose_cvt_kernel(
    const float* __restrict__ W, unsigned short* __restrict__ WT, int K, int N) {
  __shared__ float tile[32][33];
  const int j0 = blockIdx.x * 32, k0 = blockIdx.y * 32;
  const int tx = threadIdx.x, ty = threadIdx.y;
#pragma unroll
  for (int i = 0; i < 4; ++i)
    tile[ty + 8 * i][tx] = W[(size_t)(k0 + ty + 8 * i) * N + j0 + tx];
  __syncthreads();
#pragma unroll
  for (int i = 0; i < 4; ++i)
    WT[(size_t)(j0 + ty + 8 * i) * K + k0 + tx] = f2b(tile[tx][ty + 8 * i]);
}

// ---------------- f32 -> bf16 elementwise ------------------------------------
__global__ __launch_bounds__(256) void cvt_bf16_kernel(
    const float* __restrict__ in, unsigned short* __restrict__ out, int n4) {
  for (int i = blockIdx.x * blockDim.x + threadIdx.x; i < n4;
       i += gridDim.x * blockDim.x) {
    float4 v = ((const float4*)in)[i];
    uint32_t lo = (uint32_t)f2b(v.x) | ((uint32_t)f2b(v.y) << 16);
    uint32_t hi = (uint32_t)f2b(v.z) | ((uint32_t)f2b(v.w) << 16);
    ((uint2*)out)[i] = make_uint2(lo, hi);
  }
}

// ---------------- GEMM: C(MxN) = A(MxK,bf16) * B^T(NxK,bf16) + bias ----------
template <bool OUTB, bool RELU>
__global__ __launch_bounds__(512) void gemm_kernel(
    const unsigned short* __restrict__ A, const unsigned short* __restrict__ B,
    const float* __restrict__ bias, void* __restrict__ C, int M, int N, int K,
    int nbn) {
  __shared__ unsigned short As[256 * 64];  // 32 KB
  __shared__ unsigned short Bs[128 * 64];  // 16 KB

  const int tid = threadIdx.x;
  const int lane = tid & 63, wave = tid >> 6;   // wave 0..7
  const int wm = wave >> 1, wn = wave & 1;      // 4 x 2 wave grid
  const int lr = lane & 15, lk = lane >> 4;

  // XCD-chunked swizzle: consecutive chunks of the bn-fastest linear grid
  // land on one XCD (hw round-robins blockIdx % 8 across XCDs).
  const int nwg = gridDim.x;
  const int cpx = nwg >> 3;
  const int id  = blockIdx.x;
  const int wg  = (id & 7) * cpx + (id >> 3);
  const int bn  = wg % nbn;
  const int bm  = wg / nbn;

  const unsigned short* Ab = A + (size_t)bm * 256 * K;
  const unsigned short* Bb = B + (size_t)bn * 128 * K;

  // staging geometry: each issue = 512 lanes x 16B = 64 rows x 128B
  const int w8 = wave * 8 + (lane >> 3);   // row within a 64-row group
  const int sc = (lane & 7) * 8;           // col element within 64

  f32x4 acc[4][4] = {};

  for (int kt = 0; kt < K; kt += 64) {
    // ---- stage tile kt (async, direct to LDS) ----
#pragma unroll
    for (int i = 0; i < 4; ++i)
      gload_lds16(Ab + (size_t)(i * 64 + w8) * K + kt + sc,
                  &As[(i * 64 + wave * 8) * 64]);
#pragma unroll
    for (int j = 0; j < 2; ++j)
      gload_lds16(Bb + (size_t)(j * 64 + w8) * K + kt + sc,
                  &Bs[(j * 64 + wave * 8) * 64]);
    __syncthreads();  // drains vmcnt: tile resident
    // ---- compute ----
#pragma unroll
    for (int kk = 0; kk < 2; ++kk) {
      bf16x8 af[4], bfr[4];
#pragma unroll
      for (int f = 0; f < 4; ++f) {
        af[f]  = *(const bf16x8*)&As[(wm * 64 + f * 16 + lr) * 64 + (kk * 4 + lk) * 8];
        bfr[f] = *(const bf16x8*)&Bs[(wn * 64 + f * 16 + lr) * 64 + (kk * 4 + lk) * 8];
      }
#pragma unroll
      for (int mi = 0; mi < 4; ++mi)
#pragma unroll
        for (int ni = 0; ni < 4; ++ni)
          acc[mi][ni] = __builtin_amdgcn_mfma_f32_16x16x32_bf16(
              af[mi], bfr[ni], acc[mi][ni], 0, 0, 0);
    }
    __syncthreads();  // LDS consumed; next stage may overwrite
  }

  // epilogue: C/D frag layout col = lane&15, row = (lane>>4)*4 + reg
  const int orow0 = bm * 256 + wm * 64;
  const int ocol0 = bn * 128 + wn * 64;
#pragma unroll
  for (int ni = 0; ni < 4; ++ni) {
    int col = ocol0 + ni * 16 + lr;
    float bv = bias[col];
#pragma unroll
    for (int mi = 0; mi < 4; ++mi) {
#pragma unroll
      for (int r = 0; r < 4; ++r) {
        int row = orow0 + mi * 16 + lk * 4 + r;
        float val = acc[mi][ni][r] + bv;
        if (RELU) val = fmaxf(val, 0.f);
        if (OUTB)
          ((unsigned short*)C)[(size_t)row * N + col] = f2b(val);
        else
          ((float*)C)[(size_t)row * N + col] = val;
      }
    }
  }
}

// ---------------- per-position head attention --------------------------------
__global__ __launch_bounds__(256) void attn_kernel(
    const unsigned short* __restrict__ qkv, const int* __restrict__ mask,
    unsigned short* __restrict__ outb) {
  __shared__ float sq[16][68], sk[16][68], sv[16][68];
  __shared__ float sp[16][17];
  const int pos = blockIdx.x;           // n*2048 + s
  const int n = pos >> 11, s = pos & 2047;
  const int tid = threadIdx.x;
  const unsigned short* row = qkv + (size_t)pos * 3072;
#pragma unroll
  for (int it = 0; it < 3; ++it) {
    uint2 raw = *(const uint2*)(row + it * 1024 + tid * 4);
    float f0 = b2f((unsigned short)(raw.x & 0xffffu));
    float f1 = b2f((unsigned short)(raw.x >> 16));
    float f2 = b2f((unsigned short)(raw.y & 0xffffu));
    float f3 = b2f((unsigned short)(raw.y >> 16));
    float(*dst)[68] = (it == 0) ? sq : (it == 1) ? sk : sv;
    int r = tid >> 4, d = (tid & 15) * 4;
    dst[r][d] = f0; dst[r][d + 1] = f1; dst[r][d + 2] = f2; dst[r][d + 3] = f3;
  }
  __syncthreads();
  {
    const int i = tid >> 4, j = tid & 15;
    float e = 0.f;
#pragma unroll
    for (int d = 0; d < 64; d += 4) {
      float4 qa = *(const float4*)&sq[i][d];
      float4 kb = *(const float4*)&sk[j][d];
      e += qa.x * kb.x + qa.y * kb.y + qa.z * kb.z + qa.w * kb.w;
    }
    if (mask[n * 16 + j] == 0) e = -1e20f;
    e *= 0.125f;  // 1/sqrt(64)
    float mx = e;
#pragma unroll
    for (int o = 8; o > 0; o >>= 1) mx = fmaxf(mx, __shfl_xor(mx, o, 16));
    float pe = __expf(e - mx);
    float sm = pe;
#pragma unroll
    for (int o = 8; o > 0; o >>= 1) sm += __shfl_xor(sm, o, 16);
    sp[i][j] = pe / sm;
  }
  __syncthreads();
  {
    const int w = tid >> 6, d = tid & 63;
    float o0 = 0, o1 = 0, o2 = 0, o3 = 0;
#pragma unroll
    for (int l = 0; l < 16; ++l) {
      float vv = sv[l][d];
      o0 += sp[w][l] * vv;      o1 += sp[w + 4][l] * vv;
      o2 += sp[w + 8][l] * vv;  o3 += sp[w + 12][l] * vv;
    }
    outb[(((size_t)n * 16 + w     ) * 2048 + s) * 64 + d] = f2b(o0);
    outb[(((size_t)n * 16 + w + 4 ) * 2048 + s) * 64 + d] = f2b(o1);
    outb[(((size_t)n * 16 + w + 8 ) * 2048 + s) * 64 + d] = f2b(o2);
    outb[(((size_t)n * 16 + w + 12) * 2048 + s) * 64 + d] = f2b(o3);
  }
}

// ---------------- LayerNorm(A + R) * g + beta --------------------------------
__global__ __launch_bounds__(256) void ln_kernel(
    const float* __restrict__ A, const float* __restrict__ R,
    const float* __restrict__ g, const float* __restrict__ be,
    float* __restrict__ outf, unsigned short* __restrict__ outb) {
  const int row = blockIdx.x, tid = threadIdx.x;
  const size_t base = (size_t)row * 1024 + tid * 4;
  float4 a = *(const float4*)(A + base);
  float4 r = *(const float4*)(R + base);
  float x0 = a.x + r.x, x1 = a.y + r.y, x2 = a.z + r.z, x3 = a.w + r.w;
  float s = x0 + x1 + x2 + x3;
#pragma unroll
  for (int o = 32; o > 0; o >>= 1) s += __shfl_xor(s, o);
  __shared__ float red[4];
  const int lane = tid & 63, wv = tid >> 6;
  if (lane == 0) red[wv] = s;
  __syncthreads();
  float mean = (red[0] + red[1] + red[2] + red[3]) * (1.f / 1024.f);
  float d0 = x0 - mean, d1 = x1 - mean, d2 = x2 - mean, d3 = x3 - mean;
  float q = d0 * d0 + d1 * d1 + d2 * d2 + d3 * d3;
#pragma unroll
  for (int o = 32; o > 0; o >>= 1) q += __shfl_xor(q, o);
  __syncthreads();  // everyone done reading red
  if (lane == 0) red[wv] = q;
  __syncthreads();
  float var = (red[0] + red[1] + red[2] + red[3]) * (1.f / 1024.f);
  float rs = rsqrtf(var + 1e-5f);
  const int col = tid * 4;
  float4 gv = *(const float4*)(g + col);
  float4 bv = *(const float4*)(be + col);
  float y0 = d0 * rs * gv.x + bv.x;
  float y1 = d1 * rs * gv.y + bv.y;
  float y2 = d2 * rs * gv.z + bv.z;
  float y3 = d3 * rs * gv.w + bv.w;
  *(float4*)(outf + base) = make_float4(y0, y1, y2, y3);
  if (outb) {
    uint32_t lo = (uint32_t)f2b(y0) | ((uint32_t)f2b(y1) << 16);
    uint32_t hi = (uint32_t)f2b(y2) | ((uint32_t)f2b(y3) << 16);
    *(uint2*)(outb + base) = make_uint2(lo, hi);
  }
}

// ---------------- launch ------------------------------------------------------
extern "C" void kernel_launch(void* const* d_in, const int* in_sizes, int n_in,
                              void* d_out, int out_size, void* d_ws,
                              size_t ws_size, hipStream_t stream) {
  (void)in_sizes; (void)n_in; (void)out_size; (void)ws_size;
  const float* x     = (const float*)d_in[0];
  const float* Wqkv  = (const float*)d_in[1];
  const float* bqkv  = (const float*)d_in[2];
  const float* Wo    = (const float*)d_in[3];
  const float* bo    = (const float*)d_in[4];
  const float* g1    = (const float*)d_in[5];
  const float* beta1 = (const float*)d_in[6];
  const float* W1    = (const float*)d_in[7];
  const float* bf1   = (const float*)d_in[8];
  const float* W2    = (const float*)d_in[9];
  const float* bf2   = (const float*)d_in[10];
  const float* g2    = (const float*)d_in[11];
  const float* beta2 = (const float*)d_in[12];
  const int*   mask  = (const int*)d_in[13];
  float* out = (float*)d_out;

  char* ws = (char*)d_ws;
  unsigned short* WqkvT = (unsigned short*)(ws + 0);          //  6 MB
  unsigned short* WoT   = (unsigned short*)(ws + 6291456);    //  2 MB
  unsigned short* W1T   = (unsigned short*)(ws + 8388608);    //  8 MB
  unsigned short* W2T   = (unsigned short*)(ws + 16777216);   //  8 MB
  unsigned short* xb    = (unsigned short*)(ws + 25165824);   // 16 MB
  float*          h_f   = (float*)(ws + 41943040);            // 32 MB
  unsigned short* h_b   = (unsigned short*)(ws + 75497472);   // 16 MB
  float*          ao2   = (float*)(ws + 92274688);            // 32 MB (reused: ff2)
  unsigned short* qkvb  = (unsigned short*)(ws + 125829120);  // 48 MB (reused: ff1 lo)
  unsigned short* aob   = (unsigned short*)(ws + 176160768);  // 16 MB (reused: ff1 hi)
  unsigned short* ff1   = qkvb;   // 64 MB spanning qkvb+aob (dead by then)
  float*          ff2   = ao2;    // dead after LN1

  transpose_cvt_kernel<<<dim3(96, 32),  dim3(32, 8), 0, stream>>>(Wqkv, WqkvT, 1024, 3072);
  transpose_cvt_kernel<<<dim3(32, 32),  dim3(32, 8), 0, stream>>>(Wo,   WoT,   1024, 1024);
  transpose_cvt_kernel<<<dim3(128, 32), dim3(32, 8), 0, stream>>>(W1,   W1T,   1024, 4096);
  transpose_cvt_kernel<<<dim3(32, 128), dim3(32, 8), 0, stream>>>(W2,   W2T,   4096, 1024);
  cvt_bf16_kernel<<<2048, 256, 0, stream>>>(x, xb, 8192 * 1024 / 4);

  // grids: M/256 x N/128, 1D with in-kernel XCD swizzle (all % 8 == 0)
  gemm_kernel<true, false><<<dim3(32 * 24), 512, 0, stream>>>(xb, WqkvT, bqkv, qkvb, 8192, 3072, 1024, 24);
  attn_kernel<<<8192, 256, 0, stream>>>(qkvb, mask, aob);
  gemm_kernel<false, false><<<dim3(32 * 8), 512, 0, stream>>>(aob, WoT, bo, ao2, 8192, 1024, 1024, 8);
  ln_kernel<<<8192, 256, 0, stream>>>(ao2, x, g1, beta1, h_f, h_b);
  gemm_kernel<true, true><<<dim3(32 * 32), 512, 0, stream>>>(h_b, W1T, bf1, ff1, 8192, 4096, 1024, 32);
  gemm_kernel<false, false><<<dim3(32 * 8), 512, 0, stream>>>(ff1, W2T, bf2, ff2, 8192, 1024, 4096, 8);
  ln_kernel<<<8192, 256, 0, stream>>>(ff2, h_f, g2, beta2, out, nullptr);
}

// Round 3
// 329.796 us; speedup vs baseline: 3.3638x; 1.2389x over previous
//
#include <hip/hip_runtime.h>
#include <cstdint>
#include <cstddef>

// EncoderLayer: x(4,2048,1024) f32.
//   prep:  W* (KxN f32) -> W*T (NxK bf16); x f32 -> xb bf16
//   G1: qkv_b  = xb @ WqkvT + bqkv              (8192x3072, bf16 out)  BN=256
//   attn: per-position 16x16 head attention, out (N,H,S,hd) = scrambled reshape
//   G2: ao2    = aob @ WoT + bo                 (8192x1024, f32 out)   BN=128
//   LN1: h = LN(ao2 + x)  -> h_f (f32) + h_b (bf16)
//   G3: ff1_b  = relu(h_b @ W1T + bf1)          (8192x4096, bf16 out)  BN=256
//   G4: ff2    = ff1_b @ W2T + bf2              (8192x1024, f32 out)   BN=128
//   LN2: out = LN(ff2 + h_f)                    (f32 -> d_out)
//
// GEMM: 8-phase 256-row template (m201 structure): BM=256, BK=64, 512 thr
// (8 waves 2Mx4N). Per K-tile, 4 block-quadrant phases Q00,Q01,Q11,Q10;
// each phase: {ds_read frags | stage 1 half-tile via global_load_lds |
// raw s_barrier | setprio(1) MFMA setprio(0) | raw s_barrier}. Counted
// vmcnt (6 / 5) once per K-tile keeps 3 half-tiles in flight. LDS XOR
// swizzle via pre-swizzled global source + swizzled ds_read (rule #21).

using f32x4  = __attribute__((ext_vector_type(4))) float;
using bf16x8 = __attribute__((ext_vector_type(8))) __bf16;

__device__ __forceinline__ unsigned short f2b(float f) {
  union { float f; uint32_t u; } v; v.f = f;
  uint32_t r = v.u + 0x7FFFu + ((v.u >> 16) & 1u);  // RNE
  return (unsigned short)(r >> 16);
}
__device__ __forceinline__ float b2f(unsigned short u) {
  union { uint32_t u; float f; } v; v.u = ((uint32_t)u) << 16;
  return v.f;
}

__device__ __forceinline__ void gload_lds16(const unsigned short* g,
                                            unsigned short* l) {
  __builtin_amdgcn_global_load_lds(
      (const __attribute__((address_space(1))) unsigned int*)g,
      (__attribute__((address_space(3))) unsigned int*)l, 16, 0, 0);
}

#define MEMBAR() asm volatile("" ::: "memory")
__device__ __forceinline__ void barrier_raw() {
  MEMBAR();
  __builtin_amdgcn_s_barrier();
  MEMBAR();
}
template <int N>
__device__ __forceinline__ void vmwait() {
  if constexpr (N == 6)      asm volatile("s_waitcnt vmcnt(6)" ::: "memory");
  else if constexpr (N == 5) asm volatile("s_waitcnt vmcnt(5)" ::: "memory");
  else                       asm volatile("s_waitcnt vmcnt(0)" ::: "memory");
}

// ---------------- weight transpose + convert: W (KxN f32) -> WT (NxK bf16) ----
__global__ __launch_bounds__(256) void transpose_cvt_kernel(
    const float* __restrict__ W, unsigned short* __restrict__ WT, int K, int N) {
  __shared__ float tile[32][33];
  const int j0 = blockIdx.x * 32, k0 = blockIdx.y * 32;
  const int tx = threadIdx.x, ty = threadIdx.y;
#pragma unroll
  for (int i = 0; i < 4; ++i)
    tile[ty + 8 * i][tx] = W[(size_t)(k0 + ty + 8 * i) * N + j0 + tx];
  __syncthreads();
#pragma unroll
  for (int i = 0; i < 4; ++i)
    WT[(size_t)(j0 + ty + 8 * i) * K + k0 + tx] = f2b(tile[tx][ty + 8 * i]);
}

// ---------------- f32 -> bf16 elementwise ------------------------------------
__global__ __launch_bounds__(256) void cvt_bf16_kernel(
    const float* __restrict__ in, unsigned short* __restrict__ out, int n4) {
  for (int i = blockIdx.x * blockDim.x + threadIdx.x; i < n4;
       i += gridDim.x * blockDim.x) {
    float4 v = ((const float4*)in)[i];
    uint32_t lo = (uint32_t)f2b(v.x) | ((uint32_t)f2b(v.y) << 16);
    uint32_t hi = (uint32_t)f2b(v.z) | ((uint32_t)f2b(v.w) << 16);
    ((uint2*)out)[i] = make_uint2(lo, hi);
  }
}

// ---------------- GEMM: C(MxN) = A(MxK,bf16) * B^T(NxK,bf16) + bias ----------
template <int BN, bool OUTB, bool RELU>
__global__ __launch_bounds__(512, 2) void gemm8p_kernel(
    const unsigned short* __restrict__ A, const unsigned short* __restrict__ B,
    const float* __restrict__ bias, void* __restrict__ C, int M, int N, int K,
    int nbn) {
  constexpr int NF   = BN / 128;          // n-frags per quadrant per wave
  constexpr int WN   = BN / 8;            // wave col extent within a B-half
  constexpr int BH   = BN / 2;            // B half rows
  constexpr int BIS  = BN / 128;          // gload issues per B-half
  constexpr int INF  = 4 + BN / 128;      // steady-state vmcnt (loads in flight)
  constexpr int ASTR = (256 + BN) * 64;   // elements per dbuf

  __shared__ unsigned short lds[2 * ASTR];  // 128 KB (BN=256) / 96 KB (BN=128)

  const int tid  = threadIdx.x;
  const int lane = tid & 63, wave = tid >> 6;
  const int wm = wave >> 2, wn = wave & 3;  // 2 x 4 wave grid
  const int lr = lane & 15, lk = lane >> 4;
  const int x7 = lr & 7;

  // XCD-chunked swizzle, bn-fastest (all grids % 8 == 0)
  const int nwg = gridDim.x, cpx = nwg >> 3, id = blockIdx.x;
  const int wg = (id & 7) * cpx + (id >> 3);
  const int bn = wg % nbn, bm = wg / nbn;

  const unsigned short* Ab = A + (size_t)bm * 256 * K;
  const unsigned short* Bb = B + (size_t)bn * BN * K;

  // staging: per issue, 512 lanes x 16B = 64 rows x 128B; source pre-swizzled
  const int srow = tid >> 3;                       // row within 64-row group
  const int scol = ((tid & 7) ^ (srow & 7)) * 8;   // swizzled col element
  const int ldst = wave * 8 * 64;                  // wave dest offset (elems)

  const int NT = K >> 6;

  f32x4 acc[8][2 * NF] = {};
  bf16x8 aF[4][2], b0F[NF][2], b1F[NF][2];

  auto stA = [&](int t, int h, int b) {
#pragma unroll
    for (int i = 0; i < 2; ++i)
      gload_lds16(Ab + (size_t)(h * 128 + i * 64 + srow) * K + t * 64 + scol,
                  &lds[b * ASTR + (h * 128 + i * 64) * 64 + ldst]);
  };
  auto stB = [&](int t, int h, int b) {
#pragma unroll
    for (int i = 0; i < BIS; ++i)
      gload_lds16(Bb + (size_t)(h * BH + i * 64 + srow) * K + t * 64 + scol,
                  &lds[b * ASTR + 256 * 64 + (h * BH + i * 64) * 64 + ldst]);
  };
  auto rdA = [&](int b, int mh) {
#pragma unroll
    for (int mi = 0; mi < 4; ++mi) {
      int r = mh * 128 + wm * 64 + mi * 16 + lr;
#pragma unroll
      for (int kk = 0; kk < 2; ++kk)
        aF[mi][kk] = *(const bf16x8*)
            &lds[b * ASTR + r * 64 + ((kk * 4 + lk) ^ x7) * 8];
    }
  };
  auto rdB = [&](int b, int nh, bf16x8 (&bF)[NF][2]) {
#pragma unroll
    for (int ni = 0; ni < NF; ++ni) {
      int r = nh * BH + wn * WN + ni * 16 + lr;
#pragma unroll
      for (int kk = 0; kk < 2; ++kk)
        bF[ni][kk] = *(const bf16x8*)
            &lds[b * ASTR + 256 * 64 + r * 64 + ((kk * 4 + lk) ^ x7) * 8];
    }
  };
  auto mmQ = [&](bf16x8 (&bF)[NF][2], int mh, int nh) {
    __builtin_amdgcn_s_setprio(1);
#pragma unroll
    for (int mi = 0; mi < 4; ++mi)
#pragma unroll
      for (int ni = 0; ni < NF; ++ni)
#pragma unroll
        for (int kk = 0; kk < 2; ++kk)
          acc[mh * 4 + mi][nh * NF + ni] = __builtin_amdgcn_mfma_f32_16x16x32_bf16(
              aF[mi][kk], bF[ni][kk], acc[mh * 4 + mi][nh * NF + ni], 0, 0, 0);
    __builtin_amdgcn_s_setprio(0);
  };

  // ---- prologue: tile0 complete + tile1 {Ah0,Bh0,Ah1} ----
  stA(0, 0, 0); stB(0, 0, 0); stA(0, 1, 0); stB(0, 1, 0);
  stA(1, 0, 1); stB(1, 0, 1); stA(1, 1, 1);
  vmwait<INF>();   // tile0 fully resident; tile1's 3 half-tiles in flight
  barrier_raw();

  for (int t = 0; t < NT; ++t) {
    const int b = t & 1;
    const bool s1 = (t + 1 < NT), s2 = (t + 2 < NT);
    // P1: Q00 reads A(b,h0)+B(b,h0); stage Bh1(t+1) -> b^1 (free since t-1)
    rdA(b, 0);
    rdB(b, 0, b0F);
    if (s1) stB(t + 1, 1, b ^ 1);
    barrier_raw();
    mmQ(b0F, 0, 0);
    barrier_raw();
    // P2: Q01 reads B(b,h1); stage Ah0(t+2) -> b (A-h0 last read in P1)
    rdB(b, 1, b1F);
    if (s2) stA(t + 2, 0, b);
    barrier_raw();
    mmQ(b1F, 0, 1);
    barrier_raw();
    // P3: Q11 reads A(b,h1); stage Bh0(t+2) -> b (B-h0 last read in P1)
    rdA(b, 1);
    if (s2) stB(t + 2, 0, b);
    barrier_raw();
    mmQ(b1F, 1, 1);
    barrier_raw();
    // P4: Q10 (regs only); stage Ah1(t+2) -> b (A-h1 last read in P3);
    //     counted wait: tile t+1 resident, t+2's 3 half-tiles stay in flight
    if (s2) {
      stA(t + 2, 1, b);
      vmwait<INF>();
    } else if (s1) {
      vmwait<0>();
    }
    barrier_raw();
    mmQ(b0F, 1, 0);
    barrier_raw();
  }

  // ---- epilogue: C/D frag layout col = lane&15, row = (lane>>4)*4 + reg ----
  const int orow0 = bm * 256 + wm * 64;
  const int ocol0 = bn * BN + wn * WN;
#pragma unroll
  for (int mh = 0; mh < 2; ++mh)
#pragma unroll
    for (int nh = 0; nh < 2; ++nh)
#pragma unroll
      for (int ni = 0; ni < NF; ++ni) {
        int col = ocol0 + nh * BH + ni * 16 + lr;
        float bv = bias[col];
#pragma unroll
        for (int mi = 0; mi < 4; ++mi)
#pragma unroll
          for (int r = 0; r < 4; ++r) {
            int row = orow0 + mh * 128 + mi * 16 + lk * 4 + r;
            float val = acc[mh * 4 + mi][nh * NF + ni][r] + bv;
            if (RELU) val = fmaxf(val, 0.f);
            if (OUTB)
              ((unsigned short*)C)[(size_t)row * N + col] = f2b(val);
            else
              ((float*)C)[(size_t)row * N + col] = val;
          }
      }
}

// ---------------- per-position head attention --------------------------------
__global__ __launch_bounds__(256) void attn_kernel(
    const unsigned short* __restrict__ qkv, const int* __restrict__ mask,
    unsigned short* __restrict__ outb) {
  __shared__ float sq[16][68], sk[16][68], sv[16][68];
  __shared__ float sp[16][17];
  const int pos = blockIdx.x;           // n*2048 + s
  const int n = pos >> 11, s = pos & 2047;
  const int tid = threadIdx.x;
  const unsigned short* row = qkv + (size_t)pos * 3072;
#pragma unroll
  for (int it = 0; it < 3; ++it) {
    uint2 raw = *(const uint2*)(row + it * 1024 + tid * 4);
    float f0 = b2f((unsigned short)(raw.x & 0xffffu));
    float f1 = b2f((unsigned short)(raw.x >> 16));
    float f2 = b2f((unsigned short)(raw.y & 0xffffu));
    float f3 = b2f((unsigned short)(raw.y >> 16));
    float(*dst)[68] = (it == 0) ? sq : (it == 1) ? sk : sv;
    int r = tid >> 4, d = (tid & 15) * 4;
    dst[r][d] = f0; dst[r][d + 1] = f1; dst[r][d + 2] = f2; dst[r][d + 3] = f3;
  }
  __syncthreads();
  {
    const int i = tid >> 4, j = tid & 15;
    float e = 0.f;
#pragma unroll
    for (int d = 0; d < 64; d += 4) {
      float4 qa = *(const float4*)&sq[i][d];
      float4 kb = *(const float4*)&sk[j][d];
      e += qa.x * kb.x + qa.y * kb.y + qa.z * kb.z + qa.w * kb.w;
    }
    if (mask[n * 16 + j] == 0) e = -1e20f;
    e *= 0.125f;  // 1/sqrt(64)
    float mx = e;
#pragma unroll
    for (int o = 8; o > 0; o >>= 1) mx = fmaxf(mx, __shfl_xor(mx, o, 16));
    float pe = __expf(e - mx);
    float sm = pe;
#pragma unroll
    for (int o = 8; o > 0; o >>= 1) sm += __shfl_xor(sm, o, 16);
    sp[i][j] = pe / sm;
  }
  __syncthreads();
  {
    const int w = tid >> 6, d = tid & 63;
    float o0 = 0, o1 = 0, o2 = 0, o3 = 0;
#pragma unroll
    for (int l = 0; l < 16; ++l) {
      float vv = sv[l][d];
      o0 += sp[w][l] * vv;      o1 += sp[w + 4][l] * vv;
      o2 += sp[w + 8][l] * vv;  o3 += sp[w + 12][l] * vv;
    }
    outb[(((size_t)n * 16 + w     ) * 2048 + s) * 64 + d] = f2b(o0);
    outb[(((size_t)n * 16 + w + 4 ) * 2048 + s) * 64 + d] = f2b(o1);
    outb[(((size_t)n * 16 + w + 8 ) * 2048 + s) * 64 + d] = f2b(o2);
    outb[(((size_t)n * 16 + w + 12) * 2048 + s) * 64 + d] = f2b(o3);
  }
}

// ---------------- LayerNorm(A + R) * g + beta --------------------------------
__global__ __launch_bounds__(256) void ln_kernel(
    const float* __restrict__ A, const float* __restrict__ R,
    const float* __restrict__ g, const float* __restrict__ be,
    float* __restrict__ outf, unsigned short* __restrict__ outb) {
  const int row = blockIdx.x, tid = threadIdx.x;
  const size_t base = (size_t)row * 1024 + tid * 4;
  float4 a = *(const float4*)(A + base);
  float4 r = *(const float4*)(R + base);
  float x0 = a.x + r.x, x1 = a.y + r.y, x2 = a.z + r.z, x3 = a.w + r.w;
  float s = x0 + x1 + x2 + x3;
#pragma unroll
  for (int o = 32; o > 0; o >>= 1) s += __shfl_xor(s, o);
  __shared__ float red[4];
  const int lane = tid & 63, wv = tid >> 6;
  if (lane == 0) red[wv] = s;
  __syncthreads();
  float mean = (red[0] + red[1] + red[2] + red[3]) * (1.f / 1024.f);
  float d0 = x0 - mean, d1 = x1 - mean, d2 = x2 - mean, d3 = x3 - mean;
  float q = d0 * d0 + d1 * d1 + d2 * d2 + d3 * d3;
#pragma unroll
  for (int o = 32; o > 0; o >>= 1) q += __shfl_xor(q, o);
  __syncthreads();  // everyone done reading red
  if (lane == 0) red[wv] = q;
  __syncthreads();
  float var = (red[0] + red[1] + red[2] + red[3]) * (1.f / 1024.f);
  float rs = rsqrtf(var + 1e-5f);
  const int col = tid * 4;
  float4 gv = *(const float4*)(g + col);
  float4 bv = *(const float4*)(be + col);
  float y0 = d0 * rs * gv.x + bv.x;
  float y1 = d1 * rs * gv.y + bv.y;
  float y2 = d2 * rs * gv.z + bv.z;
  float y3 = d3 * rs * gv.w + bv.w;
  *(float4*)(outf + base) = make_float4(y0, y1, y2, y3);
  if (outb) {
    uint32_t lo = (uint32_t)f2b(y0) | ((uint32_t)f2b(y1) << 16);
    uint32_t hi = (uint32_t)f2b(y2) | ((uint32_t)f2b(y3) << 16);
    *(uint2*)(outb + base) = make_uint2(lo, hi);
  }
}

// ---------------- launch ------------------------------------------------------
extern "C" void kernel_launch(void* const* d_in, const int* in_sizes, int n_in,
                              void* d_out, int out_size, void* d_ws,
                              size_t ws_size, hipStream_t stream) {
  (void)in_sizes; (void)n_in; (void)out_size; (void)ws_size;
  const float* x     = (const float*)d_in[0];
  const float* Wqkv  = (const float*)d_in[1];
  const float* bqkv  = (const float*)d_in[2];
  const float* Wo    = (const float*)d_in[3];
  const float* bo    = (const float*)d_in[4];
  const float* g1    = (const float*)d_in[5];
  const float* beta1 = (const float*)d_in[6];
  const float* W1    = (const float*)d_in[7];
  const float* bf1   = (const float*)d_in[8];
  const float* W2    = (const float*)d_in[9];
  const float* bf2   = (const float*)d_in[10];
  const float* g2    = (const float*)d_in[11];
  const float* beta2 = (const float*)d_in[12];
  const int*   mask  = (const int*)d_in[13];
  float* out = (float*)d_out;

  char* ws = (char*)d_ws;
  unsigned short* WqkvT = (unsigned short*)(ws + 0);          //  6 MB
  unsigned short* WoT   = (unsigned short*)(ws + 6291456);    //  2 MB
  unsigned short* W1T   = (unsigned short*)(ws + 8388608);    //  8 MB
  unsigned short* W2T   = (unsigned short*)(ws + 16777216);   //  8 MB
  unsigned short* xb    = (unsigned short*)(ws + 25165824);   // 16 MB
  float*          h_f   = (float*)(ws + 41943040);            // 32 MB
  unsigned short* h_b   = (unsigned short*)(ws + 75497472);   // 16 MB
  float*          ao2   = (float*)(ws + 92274688);            // 32 MB (reused: ff2)
  unsigned short* qkvb  = (unsigned short*)(ws + 125829120);  // 48 MB (reused: ff1 lo)
  unsigned short* aob   = (unsigned short*)(ws + 176160768);  // 16 MB (reused: ff1 hi)
  unsigned short* ff1   = qkvb;   // 64 MB spanning qkvb+aob (dead by then)
  float*          ff2   = ao2;    // dead after LN1

  transpose_cvt_kernel<<<dim3(96, 32),  dim3(32, 8), 0, stream>>>(Wqkv, WqkvT, 1024, 3072);
  transpose_cvt_kernel<<<dim3(32, 32),  dim3(32, 8), 0, stream>>>(Wo,   WoT,   1024, 1024);
  transpose_cvt_kernel<<<dim3(128, 32), dim3(32, 8), 0, stream>>>(W1,   W1T,   1024, 4096);
  transpose_cvt_kernel<<<dim3(32, 128), dim3(32, 8), 0, stream>>>(W2,   W2T,   4096, 1024);
  cvt_bf16_kernel<<<2048, 256, 0, stream>>>(x, xb, 8192 * 1024 / 4);

  // grids: (M/256) x (N/BN), 1D with in-kernel XCD swizzle (all % 8 == 0)
  gemm8p_kernel<256, true, false><<<dim3(32 * 12), 512, 0, stream>>>(xb, WqkvT, bqkv, qkvb, 8192, 3072, 1024, 12);
  attn_kernel<<<8192, 256, 0, stream>>>(qkvb, mask, aob);
  gemm8p_kernel<128, false, false><<<dim3(32 * 8), 512, 0, stream>>>(aob, WoT, bo, ao2, 8192, 1024, 1024, 8);
  ln_kernel<<<8192, 256, 0, stream>>>(ao2, x, g1, beta1, h_f, h_b);
  gemm8p_kernel<256, true, true><<<dim3(32 * 16), 512, 0, stream>>>(h_b, W1T, bf1, ff1, 8192, 4096, 1024, 16);
  gemm8p_kernel<128, false, false><<<dim3(32 * 8), 512, 0, stream>>>(ff1, W2T, bf2, ff2, 8192, 1024, 4096, 8);
  ln_kernel<<<8192, 256, 0, stream>>>(ff2, h_f, g2, beta2, out, nullptr);
}